// Round 3
// baseline (675.670 us; speedup 1.0000x reference)
//
#include <hip/hip_runtime.h>
#include <math.h>

// TranAD fused forward, 2 blocks per batch element (grid=256, 1024 thr).
// Block (b, half) owns sequence rows [half*50, half*50+50). All stages are
// row-local except attention K/V, which is exchanged pairwise through a
// parity-double-buffered global staging area with release/acquire flags.
// Co-residency guaranteed: LDS 121KB/block > 80KB => 1 block/CU => all 256
// blocks resident on 256 CUs => pairwise spin-wait cannot deadlock.
// Flags start at 0: harness memsets the workspace every iteration.

#define TPB 1024
#define RH 50
#define SQ32 5.656854249492381f

#ifndef __has_builtin
#define __has_builtin(x) 0
#endif
#if __has_builtin(__builtin_amdgcn_exp2f)
#define EXP2(x) __builtin_amdgcn_exp2f(x)
#else
#define EXP2(x) exp2f(x)
#endif

struct KParams { const void* p[36]; };

// ---- stage weights transposed: Ws[k*(MC+4)+m] = W[m*K+k] ----
template<int K, int MC>
__device__ __forceinline__ void ldw(const float* __restrict__ Wt, float* __restrict__ Ws, int tid)
{
    constexpr int WP = MC + 4;
    for (int i = tid; i < MC * K; i += TPB) {
        int m = i / K, k = i - m * K;
        Ws[k * WP + m] = Wt[i];
    }
}

// ---- 1 row x 4 cols; WP = staged-weight pitch ----
template<int K, int WP>
__device__ __forceinline__ void gemm_row(const float* __restrict__ xrow,
                                         const float* __restrict__ wcol, float acc[4])
{
#pragma unroll 4
    for (int k = 0; k < K; ++k) {
        float xv = xrow[k];
        float4 w = *reinterpret_cast<const float4*>(wcol + k * WP);
        acc[0] = fmaf(xv, w.x, acc[0]);
        acc[1] = fmaf(xv, w.y, acc[1]);
        acc[2] = fmaf(xv, w.z, acc[2]);
        acc[3] = fmaf(xv, w.w, acc[3]);
    }
}

// q projection for own 50 rows -> Q (pitch 68)
__device__ __forceinline__ void proj_q(const float* __restrict__ Xs, const float* __restrict__ W,
                                       const float* __restrict__ Bi, float* __restrict__ Q,
                                       float* __restrict__ RW, int tid)
{
    __syncthreads();
    ldw<64, 64>(W, RW, tid);
    __syncthreads();
    const int r0 = tid >> 4, cg = tid & 15;
    if (r0 < RH) {
        float a[4] = {0, 0, 0, 0};
        gemm_row<64, 68>(Xs + r0 * 68, RW + 4 * cg, a);
        float4 bb = *reinterpret_cast<const float4*>(Bi + 4 * cg);
        *reinterpret_cast<float4*>(Q + r0 * 68 + 4 * cg) =
            make_float4(a[0] + bb.x, a[1] + bb.y, a[2] + bb.z, a[3] + bb.w);
    }
}

// k or v projection for own 50 rows -> interleaved KV[h][s] (off 0: k->xy, 2: v->zw)
__device__ __forceinline__ void proj_kv(const float* __restrict__ Xs, const float* __restrict__ W,
                                        const float* __restrict__ Bi, int off, int base,
                                        float4* __restrict__ KVs, float* __restrict__ RW, int tid)
{
    __syncthreads();
    ldw<64, 64>(W, RW, tid);
    __syncthreads();
    const int r0 = tid >> 4, cg = tid & 15;
    if (r0 < RH) {
        float a[4] = {0, 0, 0, 0};
        gemm_row<64, 68>(Xs + r0 * 68, RW + 4 * cg, a);
        float4 bb = *reinterpret_cast<const float4*>(Bi + 4 * cg);
        int sg = base + r0, h = 2 * cg;
        float* p0 = reinterpret_cast<float*>(KVs + h * 101 + sg);
        float* p1 = reinterpret_cast<float*>(KVs + (h + 1) * 101 + sg);
        *reinterpret_cast<float2*>(p0 + off) = make_float2(a[0] + bb.x, a[1] + bb.y);
        *reinterpret_cast<float2*>(p1 + off) = make_float2(a[2] + bb.z, a[3] + bb.w);
    }
}

// publish own KV half to global, set my flag = stage (release)
__device__ __forceinline__ void kv_publish(float4* __restrict__ g, int* flagme, int stage,
                                           int base, int b, const float4* __restrict__ KVs, int tid)
{
    __syncthreads();                          // KV LDS writes complete
    for (int i = tid; i < 32 * RH; i += TPB) {
        int sl = i >> 5, h = i & 31, sg = base + sl;
        g[((size_t)b * 100 + sg) * 32 + h] = KVs[h * 101 + sg];
    }
    __threadfence();                          // make my stores device-visible
    __syncthreads();
    if (tid == 0)
        __hip_atomic_store(flagme, stage, __ATOMIC_RELEASE, __HIP_MEMORY_SCOPE_AGENT);
}

// wait for partner flag >= stage (acquire), pull partner KV half into LDS
__device__ __forceinline__ void kv_waitread(const float4* __restrict__ g, int* flagpt, int stage,
                                            int pbase, int b, float4* __restrict__ KVs, int tid)
{
    if (tid == 0) {
        while (__hip_atomic_load(flagpt, __ATOMIC_ACQUIRE, __HIP_MEMORY_SCOPE_AGENT) < stage)
            __builtin_amdgcn_s_sleep(4);
    }
    __syncthreads();
    for (int i = tid; i < 32 * RH; i += TPB) {
        int sl = i >> 5, h = i & 31, sg = pbase + sl;
        KVs[h * 101 + sg] = g[((size_t)b * 100 + sg) * 32 + h];
    }
    __syncthreads();
}

// attention: own 50 q-rows, full 100-key KV. task = (head, 4-query group)
__device__ __forceinline__ void attn_block(float* __restrict__ Q,
                                           const float4* __restrict__ KVs, int tid)
{
    __syncthreads();
    if (tid < 416) {                           // 32 heads x 13 groups
        const int h = tid / 13;
        const int g = tid - 13 * h;
        const int lq0 = 4 * g;
        const float4* kv = KVs + h * 101;
        const float SCALE = 0.7071067811865476f * 1.4426950408889634f;  // /sqrt(2)*log2e
        float q0[4], q1[4];
#pragma unroll
        for (int j = 0; j < 4; ++j) {
            if (lq0 + j < RH) {
                float2 qv = *reinterpret_cast<const float2*>(Q + (lq0 + j) * 68 + 2 * h);
                q0[j] = qv.x * SCALE; q1[j] = qv.y * SCALE;
            } else { q0[j] = 0.f; q1[j] = 0.f; }
        }
        float mx[4] = {-1e30f, -1e30f, -1e30f, -1e30f};
#pragma unroll 4
        for (int s = 0; s < 100; ++s) {
            float4 k = kv[s];
#pragma unroll
            for (int j = 0; j < 4; ++j)
                mx[j] = fmaxf(mx[j], fmaf(q0[j], k.x, q1[j] * k.y));
        }
        float sum[4] = {0, 0, 0, 0}, a0[4] = {0, 0, 0, 0}, a1[4] = {0, 0, 0, 0};
#pragma unroll 4
        for (int s = 0; s < 100; ++s) {
            float4 k = kv[s];
#pragma unroll
            for (int j = 0; j < 4; ++j) {
                float e = EXP2(fmaf(q0[j], k.x, fmaf(q1[j], k.y, -mx[j])));
                sum[j] += e;
                a0[j] = fmaf(e, k.z, a0[j]);
                a1[j] = fmaf(e, k.w, a1[j]);
            }
        }
#pragma unroll
        for (int j = 0; j < 4; ++j) {
            if (lq0 + j < RH) {
                float inv = 1.f / sum[j];
                *reinterpret_cast<float2*>(Q + (lq0 + j) * 68 + 2 * h) =
                    make_float2(a0[j] * inv, a1[j] * inv);
            }
        }
    }
    __syncthreads();
}

// out-projection + residual in place on Sres (own rows)
__device__ __forceinline__ void proj_out_res(const float* __restrict__ Ain, const float* __restrict__ W,
                                             const float* __restrict__ Bi, float* __restrict__ Sres,
                                             float* __restrict__ RW, int tid)
{
    __syncthreads();
    ldw<64, 64>(W, RW, tid);
    __syncthreads();
    const int r0 = tid >> 4, cg = tid & 15;
    if (r0 < RH) {
        float a[4] = {0, 0, 0, 0};
        gemm_row<64, 68>(Ain + r0 * 68, RW + 4 * cg, a);
        float4 bb = *reinterpret_cast<const float4*>(Bi + 4 * cg);
        float* sp = Sres + r0 * 68 + 4 * cg;
        float4 s0 = *reinterpret_cast<float4*>(sp);
        *reinterpret_cast<float4*>(sp) =
            make_float4(a[0] + bb.x + s0.x, a[1] + bb.y + s0.y,
                        a[2] + bb.z + s0.z, a[3] + bb.w + s0.w);
    }
    __syncthreads();
}

// X += W2 @ (W1 @ X + b1) + b2  (LeakyReLU(True) == identity)
__device__ __forceinline__ void ffn_block(float* __restrict__ X,
                                          const float* __restrict__ W1, const float* __restrict__ B1,
                                          const float* __restrict__ W2, const float* __restrict__ B2,
                                          float* __restrict__ RW, float* __restrict__ H, int tid)
{
    __syncthreads();
    ldw<64, 16>(W1, RW, tid);
    __syncthreads();
    {
        const int r = tid >> 3, lp = tid & 7;
        if (r < RH) {
            float h0 = B1[2 * lp], h1 = B1[2 * lp + 1];
            const float* xrow = X + r * 68;
#pragma unroll 4
            for (int k = 0; k < 64; ++k) {
                float xv = xrow[k];
                h0 = fmaf(xv, RW[k * 20 + 2 * lp], h0);
                h1 = fmaf(xv, RW[k * 20 + 2 * lp + 1], h1);
            }
            H[r * 20 + 2 * lp] = h0;
            H[r * 20 + 2 * lp + 1] = h1;
        }
    }
    __syncthreads();
    ldw<16, 64>(W2, RW, tid);
    __syncthreads();
    const int r0 = tid >> 4, cg = tid & 15;
    if (r0 < RH) {
        float a[4] = {0, 0, 0, 0};
        gemm_row<16, 68>(H + r0 * 20, RW + 4 * cg, a);   // weight pitch 68, H pitch 20
        float4 bb = *reinterpret_cast<const float4*>(B2 + 4 * cg);
        float* xp = X + r0 * 68 + 4 * cg;
        float4 u = *reinterpret_cast<float4*>(xp);
        *reinterpret_cast<float4*>(xp) =
            make_float4(a[0] + bb.x + u.x, a[1] + bb.y + u.y,
                        a[2] + bb.z + u.z, a[3] + bb.w + u.w);
    }
    __syncthreads();
}

// ---------------------------------------------------------------------------
__global__ __launch_bounds__(TPB) void k_fused(KParams prm, float* __restrict__ outp,
                                               float4* __restrict__ kvx0,
                                               float4* __restrict__ kvx1,
                                               int* __restrict__ flags)
{
    __shared__ float R0[RH * 68];        // s / mem (own rows)
    __shared__ float R1[RH * 68];        // q / attn-out
    __shared__ float R3[RH * 68];        // t (own rows)
    __shared__ float4 KV[32 * 101];      // full-sequence KV, interleaved
    __shared__ float RW[64 * 68];        // staged weights
    __shared__ float Hs[RH * 20];        // FFN hidden
    __shared__ float X1s[RH * 36];       // x1 (own rows), pass0 -> pass1

    const int tid = threadIdx.x;
    const int b = blockIdx.x & 127;
    const int half = blockIdx.x >> 7;
    const int base = half * RH;
    const int pbase = RH - base;
    int* flagme = flags + (b * 2 + half) * 32;
    int* flagpt = flags + (b * 2 + (1 - half)) * 32;

    const float* src = (const float*)prm.p[0];
    const float* tgt = (const float*)prm.p[1];

    for (int pass = 0; pass < 2; ++pass) {
        const float* Weq  = (const float*)prm.p[2];
        const float* Beq  = (const float*)prm.p[3];
        const float* Weo  = (const float*)prm.p[4];
        const float* Beo  = (const float*)prm.p[5];
        const float* Wel1 = (const float*)prm.p[22];
        const float* Bel1 = (const float*)prm.p[23];
        const float* Wel2 = (const float*)prm.p[24];
        const float* Bel2 = (const float*)prm.p[25];
        const float* Wsa  = (const float*)prm.p[pass ? 14 : 6];
        const float* Bsa  = (const float*)prm.p[pass ? 15 : 7];
        const float* Wsao = (const float*)prm.p[pass ? 16 : 8];
        const float* Bsao = (const float*)prm.p[pass ? 17 : 9];
        const float* Wca  = (const float*)prm.p[pass ? 18 : 10];
        const float* Bca  = (const float*)prm.p[pass ? 19 : 11];
        const float* Wcao = (const float*)prm.p[pass ? 20 : 12];
        const float* Bcao = (const float*)prm.p[pass ? 21 : 13];
        const float* Wdl1 = (const float*)prm.p[pass ? 30 : 26];
        const float* Bdl1 = (const float*)prm.p[pass ? 31 : 27];
        const float* Wdl2 = (const float*)prm.p[pass ? 32 : 28];
        const float* Bdl2 = (const float*)prm.p[pass ? 33 : 29];
        const float* Wf   = (const float*)prm.p[34];
        const float* Bf   = (const float*)prm.p[35];
        float* outx = outp + (pass ? 409600 : 0);

        // ---- build s (own rows): s = concat(src, c)*sqrt(32) + pe ----
        __syncthreads();    // X1s (pass0 head) -> build-s read; R0 reuse
        for (int i = tid; i < RH * 64; i += TPB) {
            int l = i >> 6, d = i & 63;
            int lg = base + l;
            float sv = src[((size_t)lg * 128 + b) * 32 + (d & 31)];
            float v;
            if (d < 32) v = sv;
            else if (pass == 0) v = 0.f;
            else { float df = X1s[l * 36 + (d - 32)] - sv; v = df * df; }
            float div = __expf((float)d * -0.14391156831212787f);
            // sin(a)+cos(a) = sqrt(2)*sin(a + pi/4), fast path
            float pe = 1.4142135623730951f * __sinf((float)lg * div + 0.7853981633974483f);
            R0[l * 68 + d] = v * SQ32 + pe;
        }

        // ---- encoder self-attention + FFN on R0 (becomes mem) ----
        int st = pass * 3 + 1;
        float4* g = (st & 1) ? kvx1 : kvx0;
        proj_kv(R0, Weq + 4096, Beq + 64, 0, base, KV, RW, tid);   // K
        proj_kv(R0, Weq + 8192, Beq + 128, 2, base, KV, RW, tid);  // V
        kv_publish(g, flagme, st, base, b, KV, tid);
        proj_q(R0, Weq, Beq, R1, RW, tid);                          // overlaps exchange
        kv_waitread(g, flagpt, st, pbase, b, KV, tid);
        attn_block(R1, KV, tid);
        proj_out_res(R1, Weo, Beo, R0, RW, tid);
        ffn_block(R0, Wel1, Bel1, Wel2, Bel2, RW, Hs, tid);

        // ---- t = tile(tgt), own rows ----
        for (int i = tid; i < RH * 8; i += TPB) {
            int l = i >> 3, q4 = i & 7;
            int lg = base + l;
            float4 tv = *reinterpret_cast<const float4*>(tgt + ((size_t)lg * 128 + b) * 32 + 4 * q4);
            *reinterpret_cast<float4*>(R3 + l * 68 + 4 * q4) = tv;
            *reinterpret_cast<float4*>(R3 + l * 68 + 32 + 4 * q4) = tv;
        }

        // ---- decoder self-attention ----
        st = pass * 3 + 2;
        g = (st & 1) ? kvx1 : kvx0;
        proj_kv(R3, Wsa + 4096, Bsa + 64, 0, base, KV, RW, tid);
        proj_kv(R3, Wsa + 8192, Bsa + 128, 2, base, KV, RW, tid);
        kv_publish(g, flagme, st, base, b, KV, tid);
        proj_q(R3, Wsa, Bsa, R1, RW, tid);
        kv_waitread(g, flagpt, st, pbase, b, KV, tid);
        attn_block(R1, KV, tid);
        proj_out_res(R1, Wsao, Bsao, R3, RW, tid);

        // ---- decoder cross-attention: q from t(R3), kv from mem(R0) ----
        st = pass * 3 + 3;
        g = (st & 1) ? kvx1 : kvx0;
        proj_kv(R0, Wca + 4096, Bca + 64, 0, base, KV, RW, tid);
        proj_kv(R0, Wca + 8192, Bca + 128, 2, base, KV, RW, tid);
        kv_publish(g, flagme, st, base, b, KV, tid);
        proj_q(R3, Wca, Bca, R1, RW, tid);
        kv_waitread(g, flagpt, st, pbase, b, KV, tid);
        attn_block(R1, KV, tid);
        proj_out_res(R1, Wcao, Bcao, R3, RW, tid);
        ffn_block(R3, Wdl1, Bdl1, Wdl2, Bdl2, RW, Hs, tid);

        // ---- head: sigmoid(R3 @ Wf^T + bf) -> out (+ X1s for pass2's c) ----
        ldw<64, 32>(Wf, RW, tid);          // ffn_block ended with a barrier
        __syncthreads();
        {
            const int r = tid >> 3, lp = tid & 7;
            if (r < RH) {
                float a[4] = {0, 0, 0, 0};
                gemm_row<64, 36>(R3 + r * 68, RW + 4 * lp, a);
                float4 bb = *reinterpret_cast<const float4*>(Bf + 4 * lp);
                float o0 = 1.f / (1.f + __expf(-(a[0] + bb.x)));
                float o1 = 1.f / (1.f + __expf(-(a[1] + bb.y)));
                float o2 = 1.f / (1.f + __expf(-(a[2] + bb.z)));
                float o3 = 1.f / (1.f + __expf(-(a[3] + bb.w)));
                int rg = base + r;
                *reinterpret_cast<float4*>(outx + ((size_t)rg * 128 + b) * 32 + 4 * lp) =
                    make_float4(o0, o1, o2, o3);
                if (pass == 0)
                    *reinterpret_cast<float4*>(X1s + r * 36 + 4 * lp) =
                        make_float4(o0, o1, o2, o3);
            }
        }
    }
}

// ---------------------------------------------------------------------------
extern "C" void kernel_launch(void* const* d_in, const int* in_sizes, int n_in,
                              void* d_out, int out_size, void* d_ws, size_t ws_size,
                              hipStream_t stream)
{
    KParams prm;
    for (int i = 0; i < 36; ++i) prm.p[i] = d_in[i];
    float4* kvx0 = (float4*)d_ws;                 // 128*100*32 float4 = 6.55 MB
    float4* kvx1 = kvx0 + 409600;                 // parity double-buffer
    int* flags = (int*)(kvx1 + 409600);           // 128*2 flags, 128B apart
    k_fused<<<dim3(256), dim3(TPB), 0, stream>>>(prm, (float*)d_out, kvx0, kvx1, flags);
}

// Round 5
// 184.156 us; speedup vs baseline: 3.6690x; 3.6690x over previous
//
#include <hip/hip_runtime.h>
#include <math.h>

// TranAD fused forward, 2 blocks per batch element (grid=256, 1024 thr).
// Block (b, half) owns sequence rows [half*50, half*50+50). All stages are
// row-local except attention K/V, which is exchanged pairwise through the
// Infinity Cache using sc0 sc1 (system-coherent, L1/L2-bypass) loads/stores
// with explicit vmcnt ordering -- NO ordered atomics, NO buffer_wbl2/inv
// (round-3 post-mortem: acquire-spin invalidated L2 per poll -> 3x FETCH,
// VALUBusy 14%). Co-residency guaranteed: LDS 121KB/block => 1 block/CU =>
// all 256 blocks resident => pairwise spin cannot deadlock.
// Flags start at 0 every iteration: harness memsets the workspace.

#define TPB 1024
#define RH 50
#define SQ32 5.656854249492381f

#ifndef __has_builtin
#define __has_builtin(x) 0
#endif
#if __has_builtin(__builtin_amdgcn_exp2f)
#define EXP2(x) __builtin_amdgcn_exp2f(x)
#else
#define EXP2(x) exp2f(x)
#endif

typedef float v4f __attribute__((ext_vector_type(4)));   // native vector: legal "v" asm operand

struct KParams { const void* p[36]; };

// ---- stage weights transposed: Ws[k*(MC+4)+m] = W[m*K+k] ----
template<int K, int MC>
__device__ __forceinline__ void ldw(const float* __restrict__ Wt, float* __restrict__ Ws, int tid)
{
    constexpr int WP = MC + 4;
    for (int i = tid; i < MC * K; i += TPB) {
        int m = i / K, k = i - m * K;
        Ws[k * WP + m] = Wt[i];
    }
}

// ---- 1 row x 4 cols; WP = staged-weight pitch ----
template<int K, int WP>
__device__ __forceinline__ void gemm_row(const float* __restrict__ xrow,
                                         const float* __restrict__ wcol, float acc[4])
{
#pragma unroll 4
    for (int k = 0; k < K; ++k) {
        float xv = xrow[k];
        float4 w = *reinterpret_cast<const float4*>(wcol + k * WP);
        acc[0] = fmaf(xv, w.x, acc[0]);
        acc[1] = fmaf(xv, w.y, acc[1]);
        acc[2] = fmaf(xv, w.z, acc[2]);
        acc[3] = fmaf(xv, w.w, acc[3]);
    }
}

// q projection for own 50 rows -> Q (pitch 68)
__device__ __forceinline__ void proj_q(const float* __restrict__ Xs, const float* __restrict__ W,
                                       const float* __restrict__ Bi, float* __restrict__ Q,
                                       float* __restrict__ RW, int tid)
{
    __syncthreads();
    ldw<64, 64>(W, RW, tid);
    __syncthreads();
    const int r0 = tid >> 4, cg = tid & 15;
    if (r0 < RH) {
        float a[4] = {0, 0, 0, 0};
        gemm_row<64, 68>(Xs + r0 * 68, RW + 4 * cg, a);
        float4 bb = *reinterpret_cast<const float4*>(Bi + 4 * cg);
        *reinterpret_cast<float4*>(Q + r0 * 68 + 4 * cg) =
            make_float4(a[0] + bb.x, a[1] + bb.y, a[2] + bb.z, a[3] + bb.w);
    }
}

// k or v projection for own 50 rows -> interleaved KV[h][s] (off 0: k->xy, 2: v->zw)
__device__ __forceinline__ void proj_kv(const float* __restrict__ Xs, const float* __restrict__ W,
                                        const float* __restrict__ Bi, int off, int base,
                                        float4* __restrict__ KVs, float* __restrict__ RW, int tid)
{
    __syncthreads();
    ldw<64, 64>(W, RW, tid);
    __syncthreads();
    const int r0 = tid >> 4, cg = tid & 15;
    if (r0 < RH) {
        float a[4] = {0, 0, 0, 0};
        gemm_row<64, 68>(Xs + r0 * 68, RW + 4 * cg, a);
        float4 bb = *reinterpret_cast<const float4*>(Bi + 4 * cg);
        int sg = base + r0, h = 2 * cg;
        float* p0 = reinterpret_cast<float*>(KVs + h * 101 + sg);
        float* p1 = reinterpret_cast<float*>(KVs + (h + 1) * 101 + sg);
        *reinterpret_cast<float2*>(p0 + off) = make_float2(a[0] + bb.x, a[1] + bb.y);
        *reinterpret_cast<float2*>(p1 + off) = make_float2(a[2] + bb.z, a[3] + bb.w);
    }
}

// publish own KV half to IF$ (sc0 sc1 bypass), then raise my flag (sc0 sc1).
__device__ __forceinline__ void kv_publish(float4* __restrict__ g, int* flagme, int stage,
                                           int base, int b, const float4* __restrict__ KVs, int tid)
{
    __syncthreads();                          // KV LDS writes complete
    for (int i = tid; i < 32 * RH; i += TPB) {
        int sl = i >> 5, h = i & 31, sg = base + sl;
        v4f v = *reinterpret_cast<const v4f*>(KVs + h * 101 + sg);
        float4* p = g + ((size_t)b * 100 + sg) * 32 + h;
        asm volatile("global_store_dwordx4 %0, %1, off sc0 sc1" :: "v"(p), "v"(v) : "memory");
    }
    asm volatile("s_waitcnt vmcnt(0)" ::: "memory");   // data acked at coherence point
    __syncthreads();                                    // all threads' data out
    if (tid == 0)
        asm volatile("global_store_dword %0, %1, off sc0 sc1" :: "v"(flagme), "v"(stage) : "memory");
}

// spin (relaxed, cache-bypassing -- no L2 invalidate) until partner flag >= stage,
// then pull partner KV half from IF$ into LDS.
__device__ __forceinline__ void kv_waitread(const float4* __restrict__ g, const int* flagpt,
                                            int stage, int pbase, int b,
                                            float4* __restrict__ KVs, int tid)
{
    if (tid == 0) {
        int f;
        for (;;) {
            asm volatile("global_load_dword %0, %1, off sc0 sc1\n\ts_waitcnt vmcnt(0)"
                         : "=v"(f) : "v"(flagpt) : "memory");
            if (f >= stage) break;
            __builtin_amdgcn_s_sleep(8);
        }
    }
    __syncthreads();
    for (int i = tid; i < 32 * RH; i += TPB) {
        int sl = i >> 5, h = i & 31, sg = pbase + sl;
        const float4* p = g + ((size_t)b * 100 + sg) * 32 + h;
        v4f v;
        asm volatile("global_load_dwordx4 %0, %1, off sc0 sc1\n\ts_waitcnt vmcnt(0)"
                     : "=v"(v) : "v"(p) : "memory");
        *reinterpret_cast<v4f*>(KVs + h * 101 + sg) = v;
    }
    __syncthreads();
}

// attention: own 50 q-rows, full 100-key KV. task = (head, 4-query group)
__device__ __forceinline__ void attn_block(float* __restrict__ Q,
                                           const float4* __restrict__ KVs, int tid)
{
    __syncthreads();
    if (tid < 416) {                           // 32 heads x 13 groups
        const int h = tid / 13;
        const int g = tid - 13 * h;
        const int lq0 = 4 * g;
        const float4* kv = KVs + h * 101;
        const float SCALE = 0.7071067811865476f * 1.4426950408889634f;  // /sqrt(2)*log2e
        float q0[4], q1[4];
#pragma unroll
        for (int j = 0; j < 4; ++j) {
            if (lq0 + j < RH) {
                float2 qv = *reinterpret_cast<const float2*>(Q + (lq0 + j) * 68 + 2 * h);
                q0[j] = qv.x * SCALE; q1[j] = qv.y * SCALE;
            } else { q0[j] = 0.f; q1[j] = 0.f; }
        }
        float mx[4] = {-1e30f, -1e30f, -1e30f, -1e30f};
#pragma unroll 4
        for (int s = 0; s < 100; ++s) {
            float4 k = kv[s];
#pragma unroll
            for (int j = 0; j < 4; ++j)
                mx[j] = fmaxf(mx[j], fmaf(q0[j], k.x, q1[j] * k.y));
        }
        float sum[4] = {0, 0, 0, 0}, a0[4] = {0, 0, 0, 0}, a1[4] = {0, 0, 0, 0};
#pragma unroll 4
        for (int s = 0; s < 100; ++s) {
            float4 k = kv[s];
#pragma unroll
            for (int j = 0; j < 4; ++j) {
                float e = EXP2(fmaf(q0[j], k.x, fmaf(q1[j], k.y, -mx[j])));
                sum[j] += e;
                a0[j] = fmaf(e, k.z, a0[j]);
                a1[j] = fmaf(e, k.w, a1[j]);
            }
        }
#pragma unroll
        for (int j = 0; j < 4; ++j) {
            if (lq0 + j < RH) {
                float inv = 1.f / sum[j];
                *reinterpret_cast<float2*>(Q + (lq0 + j) * 68 + 2 * h) =
                    make_float2(a0[j] * inv, a1[j] * inv);
            }
        }
    }
    __syncthreads();
}

// out-projection + residual in place on Sres (own rows)
__device__ __forceinline__ void proj_out_res(const float* __restrict__ Ain, const float* __restrict__ W,
                                             const float* __restrict__ Bi, float* __restrict__ Sres,
                                             float* __restrict__ RW, int tid)
{
    __syncthreads();
    ldw<64, 64>(W, RW, tid);
    __syncthreads();
    const int r0 = tid >> 4, cg = tid & 15;
    if (r0 < RH) {
        float a[4] = {0, 0, 0, 0};
        gemm_row<64, 68>(Ain + r0 * 68, RW + 4 * cg, a);
        float4 bb = *reinterpret_cast<const float4*>(Bi + 4 * cg);
        float* sp = Sres + r0 * 68 + 4 * cg;
        float4 s0 = *reinterpret_cast<float4*>(sp);
        *reinterpret_cast<float4*>(sp) =
            make_float4(a[0] + bb.x + s0.x, a[1] + bb.y + s0.y,
                        a[2] + bb.z + s0.z, a[3] + bb.w + s0.w);
    }
    __syncthreads();
}

// X += W2 @ (W1 @ X + b1) + b2  (LeakyReLU(True) == identity)
__device__ __forceinline__ void ffn_block(float* __restrict__ X,
                                          const float* __restrict__ W1, const float* __restrict__ B1,
                                          const float* __restrict__ W2, const float* __restrict__ B2,
                                          float* __restrict__ RW, float* __restrict__ H, int tid)
{
    __syncthreads();
    ldw<64, 16>(W1, RW, tid);
    __syncthreads();
    {
        const int r = tid >> 3, lp = tid & 7;
        if (r < RH) {
            float h0 = B1[2 * lp], h1 = B1[2 * lp + 1];
            const float* xrow = X + r * 68;
#pragma unroll 4
            for (int k = 0; k < 64; ++k) {
                float xv = xrow[k];
                h0 = fmaf(xv, RW[k * 20 + 2 * lp], h0);
                h1 = fmaf(xv, RW[k * 20 + 2 * lp + 1], h1);
            }
            H[r * 20 + 2 * lp] = h0;
            H[r * 20 + 2 * lp + 1] = h1;
        }
    }
    __syncthreads();
    ldw<16, 64>(W2, RW, tid);
    __syncthreads();
    const int r0 = tid >> 4, cg = tid & 15;
    if (r0 < RH) {
        float a[4] = {0, 0, 0, 0};
        gemm_row<16, 68>(H + r0 * 20, RW + 4 * cg, a);   // weight pitch 68, H pitch 20
        float4 bb = *reinterpret_cast<const float4*>(B2 + 4 * cg);
        float* xp = X + r0 * 68 + 4 * cg;
        float4 u = *reinterpret_cast<float4*>(xp);
        *reinterpret_cast<float4*>(xp) =
            make_float4(a[0] + bb.x + u.x, a[1] + bb.y + u.y,
                        a[2] + bb.z + u.z, a[3] + bb.w + u.w);
    }
    __syncthreads();
}

// ---------------------------------------------------------------------------
__global__ __launch_bounds__(TPB) void k_fused(KParams prm, float* __restrict__ outp,
                                               float4* __restrict__ kvx0,
                                               float4* __restrict__ kvx1,
                                               int* __restrict__ flags)
{
    __shared__ float R0[RH * 68];        // s / mem (own rows)
    __shared__ float R1[RH * 68];        // q / attn-out
    __shared__ float R3[RH * 68];        // t (own rows)
    __shared__ float4 KV[32 * 101];      // full-sequence KV, interleaved
    __shared__ float RW[64 * 68];        // staged weights
    __shared__ float Hs[RH * 20];        // FFN hidden
    __shared__ float X1s[RH * 36];       // x1 (own rows), pass0 -> pass1

    const int tid = threadIdx.x;
    const int b = blockIdx.x & 127;
    const int half = blockIdx.x >> 7;
    const int base = half * RH;
    const int pbase = RH - base;
    int* flagme = flags + (b * 2 + half) * 32;
    int* flagpt = flags + (b * 2 + (1 - half)) * 32;

    const float* src = (const float*)prm.p[0];
    const float* tgt = (const float*)prm.p[1];

    for (int pass = 0; pass < 2; ++pass) {
        const float* Weq  = (const float*)prm.p[2];
        const float* Beq  = (const float*)prm.p[3];
        const float* Weo  = (const float*)prm.p[4];
        const float* Beo  = (const float*)prm.p[5];
        const float* Wel1 = (const float*)prm.p[22];
        const float* Bel1 = (const float*)prm.p[23];
        const float* Wel2 = (const float*)prm.p[24];
        const float* Bel2 = (const float*)prm.p[25];
        const float* Wsa  = (const float*)prm.p[pass ? 14 : 6];
        const float* Bsa  = (const float*)prm.p[pass ? 15 : 7];
        const float* Wsao = (const float*)prm.p[pass ? 16 : 8];
        const float* Bsao = (const float*)prm.p[pass ? 17 : 9];
        const float* Wca  = (const float*)prm.p[pass ? 18 : 10];
        const float* Bca  = (const float*)prm.p[pass ? 19 : 11];
        const float* Wcao = (const float*)prm.p[pass ? 20 : 12];
        const float* Bcao = (const float*)prm.p[pass ? 21 : 13];
        const float* Wdl1 = (const float*)prm.p[pass ? 30 : 26];
        const float* Bdl1 = (const float*)prm.p[pass ? 31 : 27];
        const float* Wdl2 = (const float*)prm.p[pass ? 32 : 28];
        const float* Bdl2 = (const float*)prm.p[pass ? 33 : 29];
        const float* Wf   = (const float*)prm.p[34];
        const float* Bf   = (const float*)prm.p[35];
        float* outx = outp + (pass ? 409600 : 0);

        // ---- build s (own rows): s = concat(src, c)*sqrt(32) + pe ----
        __syncthreads();    // X1s (pass0 head) -> build-s read; R0 reuse
        for (int i = tid; i < RH * 64; i += TPB) {
            int l = i >> 6, d = i & 63;
            int lg = base + l;
            float sv = src[((size_t)lg * 128 + b) * 32 + (d & 31)];
            float v;
            if (d < 32) v = sv;
            else if (pass == 0) v = 0.f;
            else { float df = X1s[l * 36 + (d - 32)] - sv; v = df * df; }
            float div = __expf((float)d * -0.14391156831212787f);
            // sin(a)+cos(a) = sqrt(2)*sin(a + pi/4), fast path
            float pe = 1.4142135623730951f * __sinf((float)lg * div + 0.7853981633974483f);
            R0[l * 68 + d] = v * SQ32 + pe;
        }

        // ---- encoder self-attention + FFN on R0 (becomes mem) ----
        int st = pass * 3 + 1;
        float4* g = (st & 1) ? kvx1 : kvx0;
        proj_kv(R0, Weq + 4096, Beq + 64, 0, base, KV, RW, tid);   // K
        proj_kv(R0, Weq + 8192, Beq + 128, 2, base, KV, RW, tid);  // V
        kv_publish(g, flagme, st, base, b, KV, tid);
        proj_q(R0, Weq, Beq, R1, RW, tid);                          // overlaps exchange
        kv_waitread(g, flagpt, st, pbase, b, KV, tid);
        attn_block(R1, KV, tid);
        proj_out_res(R1, Weo, Beo, R0, RW, tid);
        ffn_block(R0, Wel1, Bel1, Wel2, Bel2, RW, Hs, tid);

        // ---- t = tile(tgt), own rows ----
        for (int i = tid; i < RH * 8; i += TPB) {
            int l = i >> 3, q4 = i & 7;
            int lg = base + l;
            float4 tv = *reinterpret_cast<const float4*>(tgt + ((size_t)lg * 128 + b) * 32 + 4 * q4);
            *reinterpret_cast<float4*>(R3 + l * 68 + 4 * q4) = tv;
            *reinterpret_cast<float4*>(R3 + l * 68 + 32 + 4 * q4) = tv;
        }

        // ---- decoder self-attention ----
        st = pass * 3 + 2;
        g = (st & 1) ? kvx1 : kvx0;
        proj_kv(R3, Wsa + 4096, Bsa + 64, 0, base, KV, RW, tid);
        proj_kv(R3, Wsa + 8192, Bsa + 128, 2, base, KV, RW, tid);
        kv_publish(g, flagme, st, base, b, KV, tid);
        proj_q(R3, Wsa, Bsa, R1, RW, tid);
        kv_waitread(g, flagpt, st, pbase, b, KV, tid);
        attn_block(R1, KV, tid);
        proj_out_res(R1, Wsao, Bsao, R3, RW, tid);

        // ---- decoder cross-attention: q from t(R3), kv from mem(R0) ----
        st = pass * 3 + 3;
        g = (st & 1) ? kvx1 : kvx0;
        proj_kv(R0, Wca + 4096, Bca + 64, 0, base, KV, RW, tid);
        proj_kv(R0, Wca + 8192, Bca + 128, 2, base, KV, RW, tid);
        kv_publish(g, flagme, st, base, b, KV, tid);
        proj_q(R3, Wca, Bca, R1, RW, tid);
        kv_waitread(g, flagpt, st, pbase, b, KV, tid);
        attn_block(R1, KV, tid);
        proj_out_res(R1, Wcao, Bcao, R3, RW, tid);
        ffn_block(R3, Wdl1, Bdl1, Wdl2, Bdl2, RW, Hs, tid);

        // ---- head: sigmoid(R3 @ Wf^T + bf) -> out (+ X1s for pass2's c) ----
        ldw<64, 32>(Wf, RW, tid);          // ffn_block ended with a barrier
        __syncthreads();
        {
            const int r = tid >> 3, lp = tid & 7;
            if (r < RH) {
                float a[4] = {0, 0, 0, 0};
                gemm_row<64, 36>(R3 + r * 68, RW + 4 * lp, a);
                float4 bb = *reinterpret_cast<const float4*>(Bf + 4 * lp);
                float o0 = 1.f / (1.f + __expf(-(a[0] + bb.x)));
                float o1 = 1.f / (1.f + __expf(-(a[1] + bb.y)));
                float o2 = 1.f / (1.f + __expf(-(a[2] + bb.z)));
                float o3 = 1.f / (1.f + __expf(-(a[3] + bb.w)));
                int rg = base + r;
                *reinterpret_cast<float4*>(outx + ((size_t)rg * 128 + b) * 32 + 4 * lp) =
                    make_float4(o0, o1, o2, o3);
                if (pass == 0)
                    *reinterpret_cast<float4*>(X1s + r * 36 + 4 * lp) =
                        make_float4(o0, o1, o2, o3);
            }
        }
    }
}

// ---------------------------------------------------------------------------
extern "C" void kernel_launch(void* const* d_in, const int* in_sizes, int n_in,
                              void* d_out, int out_size, void* d_ws, size_t ws_size,
                              hipStream_t stream)
{
    KParams prm;
    for (int i = 0; i < 36; ++i) prm.p[i] = d_in[i];
    float4* kvx0 = (float4*)d_ws;                 // 128*100*32 float4 = 6.55 MB
    float4* kvx1 = kvx0 + 409600;                 // parity double-buffer
    int* flags = (int*)(kvx1 + 409600);           // 128*2 flags, 128B apart
    k_fused<<<dim3(256), dim3(TPB), 0, stream>>>(prm, (float*)d_out, kvx0, kvx1, flags);
}